// Round 8
// baseline (42.700 us; speedup 1.0000x reference)
//
#include <hip/hip_runtime.h>

// NeRF backbone builder — 2-wave-per-chain, S=4, PROVEN step3 math only.
// (Fast rigid-geometry math convicted by R4/R5/R7 bisect — reverted for good.)
// Wave 0: chunks 0..63 (steps 0..255); wave 1: chunks 64..127 (steps 256..510).
// pass1 chunk transforms (renormalizing step3) -> per-wave 6-level scan ->
// wave0 publishes total via LDS -> world replay staged to swizzled LDS ->
// 128-thread coalesced float4 flush. 18.4KB LDS/128thr -> 16 waves/CU.

struct V3 { float x, y, z; };

__device__ __forceinline__ V3 vsub(V3 a, V3 b){ return {a.x-b.x, a.y-b.y, a.z-b.z}; }
__device__ __forceinline__ V3 vcross(V3 a, V3 b){
    return {a.y*b.z - a.z*b.y, a.z*b.x - a.x*b.z, a.x*b.y - a.y*b.x};
}
__device__ __forceinline__ float vdot(V3 a, V3 b){ return a.x*b.x + a.y*b.y + a.z*b.z; }
__device__ __forceinline__ V3 vunit(V3 a){
    float r = rsqrtf(vdot(a,a));
    return {a.x*r, a.y*r, a.z*r};
}

struct Xform { V3 c0, c1, c2, t; };  // p' = c0*px + c1*py + c2*pz + t

__device__ __forceinline__ V3 xrot(const Xform& X, V3 p){
    return { X.c0.x*p.x + X.c1.x*p.y + X.c2.x*p.z,
             X.c0.y*p.x + X.c1.y*p.y + X.c2.y*p.z,
             X.c0.z*p.x + X.c1.z*p.y + X.c2.z*p.z };
}
__device__ __forceinline__ V3 xapply(const Xform& X, V3 p){
    V3 r = xrot(X, p);
    return { r.x + X.t.x, r.y + X.t.y, r.z + X.t.z };
}
__device__ __forceinline__ Xform xcompose(const Xform& A, const Xform& B){ // A∘B (B first)
    Xform R;
    R.c0 = xrot(A, B.c0);
    R.c1 = xrot(A, B.c1);
    R.c2 = xrot(A, B.c2);
    R.t  = xapply(A, B.t);
    return R;
}

__device__ __forceinline__ Xform frame_of(V3 A, V3 B, V3 C){
    V3 bc  = vunit(vsub(C, B));
    V3 n   = vunit(vcross(vsub(B, A), bc));
    V3 nbc = vcross(n, bc);
    return { bc, nbc, n, C };
}

__device__ __forceinline__ Xform shfl_up_xf(const Xform& X, int d){
    Xform R;
    R.c0.x = __shfl_up(X.c0.x, d); R.c0.y = __shfl_up(X.c0.y, d); R.c0.z = __shfl_up(X.c0.z, d);
    R.c1.x = __shfl_up(X.c1.x, d); R.c1.y = __shfl_up(X.c1.y, d); R.c1.z = __shfl_up(X.c1.z, d);
    R.c2.x = __shfl_up(X.c2.x, d); R.c2.y = __shfl_up(X.c2.y, d); R.c2.z = __shfl_up(X.c2.z, d);
    R.t.x  = __shfl_up(X.t.x,  d); R.t.y  = __shfl_up(X.t.y,  d); R.t.z  = __shfl_up(X.t.z,  d);
    return R;
}

// Bond constants: d0 = -L*cos(theta), Ls = L*sin(theta)
#define D0_CN   0.56630847f
#define LS_CN   1.21445243f
#define D0_NCA  0.75195559f
#define LS_NCA  1.25146426f
#define D0_CAC  0.50137496f
#define LS_CAC  1.45609861f

// Canonical incoming triple in its own frame (HW-validated R2/R3/R6)
#define A0X (-2.0153295f)
#define A0Y ( 1.3804571f)

// World init triple
#define NIX 17.047f
#define NIY 14.099f
#define NIZ  3.625f
#define CAX 16.967f
#define CAY 12.784f
#define CAZ  4.338f
#define CIX 15.685f
#define CIY 12.755f
#define CIZ  5.133f

__device__ __forceinline__ V3 place_dihedral(V3 a, V3 b, V3 c,
                                             float d0, float Ls, float tor){
    V3 ab = vsub(b, a);
    V3 bc = vunit(vsub(c, b));
    V3 n  = vunit(vcross(ab, bc));
    V3 nbc = vcross(n, bc);
    float sn, cs;
    __sincosf(tor, &sn, &cs);
    float d1 = Ls * cs;
    float d2 = Ls * sn;
    return { c.x + d0*bc.x + d1*nbc.x + d2*n.x,
             c.y + d0*bc.y + d1*nbc.y + d2*n.y,
             c.z + d0*bc.z + d1*nbc.z + d2*n.z };
}

__device__ __forceinline__ void step3(V3& A, V3& B, V3& C,
                                      float tpsi, float tome, float tphi){
    V3 dn  = place_dihedral(A, B, C,  D0_CN,  LS_CN,  tpsi);
    V3 dca = place_dihedral(B, C, dn, D0_NCA, LS_NCA, tome);
    V3 dc  = place_dihedral(C, dn, dca, D0_CAC, LS_CAC, tphi);
    A = dn; B = dca; C = dc;
}

// LDS float-index swizzle (involution, float4-consistent) — HW-validated R6.
__device__ __forceinline__ int swz(int F){ return F ^ (((F >> 8) & 7) << 2); }

__device__ __forceinline__ void stage_row(float* lds, int r, V3 a, V3 b, V3 c){
    int base = r * 9;
    lds[swz(base+0)] = a.x; lds[swz(base+1)] = a.y; lds[swz(base+2)] = a.z;
    lds[swz(base+3)] = b.x; lds[swz(base+4)] = b.y; lds[swz(base+5)] = b.z;
    lds[swz(base+6)] = c.x; lds[swz(base+7)] = c.y; lds[swz(base+8)] = c.z;
}

// ---- Fused kernel (steps==511, L==512): two waves per chain, S=4 ----
__global__ __launch_bounds__(128, 4)
void nerf_wave2(const float* __restrict__ phi,
                const float* __restrict__ psi,
                const float* __restrict__ omega,
                float* __restrict__ out,
                int steps){
    const int L = 512;
    int b   = blockIdx.x;
    int tid = threadIdx.x;
    int w   = tid >> 6;                 // wave 0 / 1
    int k   = tid & 63;                 // lane in wave

    __shared__ float lds[4608];         // full chain, swizzled (18432 B)
    __shared__ float wc[12];            // wave0 total transform handoff

    const float* pphi = phi   + (size_t)b * L;
    const float* ppsi = psi   + (size_t)b * L;
    const float* pome = omega + (size_t)b * L;

    int s0 = tid << 2;                  // first step of this chunk (4*tid)

    float4 ps = *(const float4*)(ppsi + s0);
    float4 om = *(const float4*)(pome + s0);
    float4 ph = *(const float4*)(pphi + s0);
    float phn = __shfl_down(ph.x, 1);               // phi[s0+4] from lane k+1
    if (k == 63) phn = (w == 0) ? pphi[256] : 0.f;  // w1 k63 s3 is masked anyway
    float tpsi[4] = {ps.x, ps.y, ps.z, ps.w};
    float tome[4] = {om.x, om.y, om.z, om.w};
    float tphi[4] = {ph.y, ph.z, ph.w, phn};

    // ---- pass 1: chunk transform (renormalizing step3 — general path) ----
    V3 A, Bv, C;
    if (tid == 0){
        A = {NIX, NIY, NIZ}; Bv = {CAX, CAY, CAZ}; C = {CIX, CIY, CIZ};
    } else {
        A = {A0X, A0Y, 0.f}; Bv = {-1.54f, 0.f, 0.f}; C = {0.f, 0.f, 0.f};
    }
    #pragma unroll
    for (int s = 0; s < 4; ++s){
        if (s0 + s < steps)
            step3(A, Bv, C, tpsi[s], tome[s], tphi[s]);
    }
    Xform V = frame_of(A, Bv, C);

    // ---- per-wave inclusive scan: V_k = M_(w*64) ∘ ... ∘ M_(w*64+k) ----
    #pragma unroll
    for (int d = 1; d < 64; d <<= 1){
        Xform Pr = shfl_up_xf(V, d);
        if (k >= d) V = xcompose(Pr, V);
    }
    Xform Vp = shfl_up_xf(V, 1);        // wave-local prefix through lane k-1

    if (w == 0 && k == 63){             // publish wave0 total (through step 255)
        wc[0]=V.c0.x; wc[1]=V.c0.y; wc[2]=V.c0.z;
        wc[3]=V.c1.x; wc[4]=V.c1.y; wc[5]=V.c1.z;
        wc[6]=V.c2.x; wc[7]=V.c2.y; wc[8]=V.c2.z;
        wc[9]=V.t.x;  wc[10]=V.t.y; wc[11]=V.t.z;
    }
    __syncthreads();

    // ---- pass 3: world replay + swizzled staging ----
    if (tid == 0){
        A = {NIX, NIY, NIZ}; Bv = {CAX, CAY, CAZ}; C = {CIX, CIY, CIZ};
        stage_row(lds, 0, A, Bv, C);                // row 0: init triple
    } else {
        Xform W;
        if (w == 0){
            W = Vp;
        } else {
            Xform Wc;
            Wc.c0 = {wc[0],wc[1],wc[2]};
            Wc.c1 = {wc[3],wc[4],wc[5]};
            Wc.c2 = {wc[6],wc[7],wc[8]};
            Wc.t  = {wc[9],wc[10],wc[11]};
            W = (k == 0) ? Wc : xcompose(Wc, Vp);
        }
        A  = xapply(W, {A0X, A0Y, 0.f});
        Bv = xapply(W, {-1.54f, 0.f, 0.f});
        C  = W.t;
    }
    #pragma unroll
    for (int s = 0; s < 4; ++s){
        if (s0 + s < steps){
            step3(A, Bv, C, tpsi[s], tome[s], tphi[s]);
            stage_row(lds, s0 + s + 1, A, Bv, C);   // row = step+1
        }
    }
    __syncthreads();

    // ---- flush: 1152 float4, 128 threads x 9 iters, lane-consecutive ----
    float4* ol = (float4*)(out + (size_t)b * 4608u);
    const float4* ls = (const float4*)lds;
    #pragma unroll
    for (int i = 0; i < 9; ++i){
        int q = i * 128 + tid;
        ol[q] = ls[q ^ ((q >> 6) & 7)];
    }
}

// ---- Fallback: sequential one-thread-per-chain (general sizes) ----
__global__ void nerf_seq_kernel(const float* __restrict__ phi,
                                const float* __restrict__ psi,
                                const float* __restrict__ omega,
                                float* __restrict__ out,
                                int B, int L, int steps){
    int b = blockIdx.x * blockDim.x + threadIdx.x;
    if (b >= B) return;
    V3 A  = {NIX, NIY, NIZ};
    V3 Bv = {CAX, CAY, CAZ};
    V3 C  = {CIX, CIY, CIZ};
    float* o = out + (size_t)b * 9u * (size_t)(steps + 1);
    o[0]=A.x;  o[1]=A.y;  o[2]=A.z;
    o[3]=Bv.x; o[4]=Bv.y; o[5]=Bv.z;
    o[6]=C.x;  o[7]=C.y;  o[8]=C.z;
    const float* pphi = phi   + (size_t)b * L;
    const float* ppsi = psi   + (size_t)b * L;
    const float* pome = omega + (size_t)b * L;
    for (int s = 0; s < steps; ++s){
        step3(A, Bv, C, ppsi[s], pome[s], pphi[s + 1]);
        float* os = o + 9u * (size_t)(s + 1);
        os[0]=A.x;  os[1]=A.y;  os[2]=A.z;
        os[3]=Bv.x; os[4]=Bv.y; os[5]=Bv.z;
        os[6]=C.x;  os[7]=C.y;  os[8]=C.z;
    }
}

extern "C" void kernel_launch(void* const* d_in, const int* in_sizes, int n_in,
                              void* d_out, int out_size, void* d_ws, size_t ws_size,
                              hipStream_t stream) {
    const float* phi   = (const float*)d_in[0];
    const float* psi   = (const float*)d_in[1];
    const float* omega = (const float*)d_in[2];
    float* out = (float*)d_out;

    const int L = 512;
    int B = in_sizes[0] / L;
    int steps = out_size / (9 * B) - 1;

    if (steps == 511 && in_sizes[0] == B * 512) {
        nerf_wave2<<<B, 128, 0, stream>>>(phi, psi, omega, out, steps);
    } else {
        int block = 64;
        int grid = (B + block - 1) / block;
        nerf_seq_kernel<<<grid, block, 0, stream>>>(phi, psi, omega, out, B, L, steps);
    }
}

// Round 9
// 34.259 us; speedup vs baseline: 1.2464x; 1.2464x over previous
//
#include <hip/hip_runtime.h>

// NeRF backbone builder — R6 proven structure (1 wave/chain, S=8, step3 math,
// swizzled LDS, float4 flush) with ONE structural change: pass-3 world REPLAY
// (full step3 per step) replaced by rigid TRANSFORM of pass-1 local atoms
// (xapply per atom). Halves step3 work; single scan.

struct V3 { float x, y, z; };

__device__ __forceinline__ V3 vsub(V3 a, V3 b){ return {a.x-b.x, a.y-b.y, a.z-b.z}; }
__device__ __forceinline__ V3 vcross(V3 a, V3 b){
    return {a.y*b.z - a.z*b.y, a.z*b.x - a.x*b.z, a.x*b.y - a.y*b.x};
}
__device__ __forceinline__ float vdot(V3 a, V3 b){ return a.x*b.x + a.y*b.y + a.z*b.z; }
__device__ __forceinline__ V3 vunit(V3 a){
    float r = rsqrtf(vdot(a,a));
    return {a.x*r, a.y*r, a.z*r};
}

struct Xform { V3 c0, c1, c2, t; };  // p' = c0*px + c1*py + c2*pz + t

__device__ __forceinline__ V3 xrot(const Xform& X, V3 p){
    return { X.c0.x*p.x + X.c1.x*p.y + X.c2.x*p.z,
             X.c0.y*p.x + X.c1.y*p.y + X.c2.y*p.z,
             X.c0.z*p.x + X.c1.z*p.y + X.c2.z*p.z };
}
__device__ __forceinline__ V3 xapply(const Xform& X, V3 p){
    V3 r = xrot(X, p);
    return { r.x + X.t.x, r.y + X.t.y, r.z + X.t.z };
}
__device__ __forceinline__ Xform xcompose(const Xform& A, const Xform& B){ // A∘B (B first)
    Xform R;
    R.c0 = xrot(A, B.c0);
    R.c1 = xrot(A, B.c1);
    R.c2 = xrot(A, B.c2);
    R.t  = xapply(A, B.t);
    return R;
}

__device__ __forceinline__ Xform frame_of(V3 A, V3 B, V3 C){
    V3 bc  = vunit(vsub(C, B));
    V3 n   = vunit(vcross(vsub(B, A), bc));
    V3 nbc = vcross(n, bc);
    return { bc, nbc, n, C };
}

__device__ __forceinline__ Xform shfl_up_xf(const Xform& X, int d){
    Xform R;
    R.c0.x = __shfl_up(X.c0.x, d); R.c0.y = __shfl_up(X.c0.y, d); R.c0.z = __shfl_up(X.c0.z, d);
    R.c1.x = __shfl_up(X.c1.x, d); R.c1.y = __shfl_up(X.c1.y, d); R.c1.z = __shfl_up(X.c1.z, d);
    R.c2.x = __shfl_up(X.c2.x, d); R.c2.y = __shfl_up(X.c2.y, d); R.c2.z = __shfl_up(X.c2.z, d);
    R.t.x  = __shfl_up(X.t.x,  d); R.t.y  = __shfl_up(X.t.y,  d); R.t.z  = __shfl_up(X.t.z,  d);
    return R;
}

// Bond constants: d0 = -L*cos(theta), Ls = L*sin(theta)
#define D0_CN   0.56630847f
#define LS_CN   1.21445243f
#define D0_NCA  0.75195559f
#define LS_NCA  1.25146426f
#define D0_CAC  0.50137496f
#define LS_CAC  1.45609861f

// Canonical incoming triple in its own frame (HW-validated R2/R3/R6/R8)
#define A0X (-2.0153295f)
#define A0Y ( 1.3804571f)

// World init triple
#define NIX 17.047f
#define NIY 14.099f
#define NIZ  3.625f
#define CAX 16.967f
#define CAY 12.784f
#define CAZ  4.338f
#define CIX 15.685f
#define CIY 12.755f
#define CIZ  5.133f

__device__ __forceinline__ V3 place_dihedral(V3 a, V3 b, V3 c,
                                             float d0, float Ls, float tor){
    V3 ab = vsub(b, a);
    V3 bc = vunit(vsub(c, b));
    V3 n  = vunit(vcross(ab, bc));
    V3 nbc = vcross(n, bc);
    float sn, cs;
    __sincosf(tor, &sn, &cs);
    float d1 = Ls * cs;
    float d2 = Ls * sn;
    return { c.x + d0*bc.x + d1*nbc.x + d2*n.x,
             c.y + d0*bc.y + d1*nbc.y + d2*n.y,
             c.z + d0*bc.z + d1*nbc.z + d2*n.z };
}

__device__ __forceinline__ void step3(V3& A, V3& B, V3& C,
                                      float tpsi, float tome, float tphi){
    V3 dn  = place_dihedral(A, B, C,  D0_CN,  LS_CN,  tpsi);
    V3 dca = place_dihedral(B, C, dn, D0_NCA, LS_NCA, tome);
    V3 dc  = place_dihedral(C, dn, dca, D0_CAC, LS_CAC, tphi);
    A = dn; B = dca; C = dc;
}

// LDS float-index swizzle (involution, float4-consistent) — HW-validated R6/R8.
__device__ __forceinline__ int swz(int F){ return F ^ (((F >> 8) & 7) << 2); }

__device__ __forceinline__ void stage_row(float* lds, int r, V3 a, V3 b, V3 c){
    int base = r * 9;
    lds[swz(base+0)] = a.x; lds[swz(base+1)] = a.y; lds[swz(base+2)] = a.z;
    lds[swz(base+3)] = b.x; lds[swz(base+4)] = b.y; lds[swz(base+5)] = b.z;
    lds[swz(base+6)] = c.x; lds[swz(base+7)] = c.y; lds[swz(base+8)] = c.z;
}

// ---- Fused kernel: one wave per chain (steps == 511, L == 512) ----
__global__ __launch_bounds__(64, 2)
void nerf_wave(const float* __restrict__ phi,
               const float* __restrict__ psi,
               const float* __restrict__ omega,
               float* __restrict__ out,
               int steps){
    const int L = 512;
    const int S = 8;
    int b = blockIdx.x;
    int k = threadIdx.x;              // chunk id 0..63
    int s0 = k * S;

    __shared__ float lds[4608];       // 18432 B, swizzled

    const float* pphi = phi   + (size_t)b * L;
    const float* ppsi = psi   + (size_t)b * L;
    const float* pome = omega + (size_t)b * L;

    float4 ps0 = ((const float4*)(ppsi + s0))[0];
    float4 ps1 = ((const float4*)(ppsi + s0))[1];
    float4 om0 = ((const float4*)(pome + s0))[0];
    float4 om1 = ((const float4*)(pome + s0))[1];
    float4 ph0 = ((const float4*)(pphi + s0))[0];
    float4 ph1 = ((const float4*)(pphi + s0))[1];
    float phi8 = __shfl_down(ph0.x, 1);   // phi[s0+8] from lane k+1 (unused at k=63)

    float tpsi[8] = {ps0.x, ps0.y, ps0.z, ps0.w, ps1.x, ps1.y, ps1.z, ps1.w};
    float tome[8] = {om0.x, om0.y, om0.z, om0.w, om1.x, om1.y, om1.z, om1.w};
    float tphi[8] = {ph0.y, ph0.z, ph0.w, ph1.x, ph1.y, ph1.z, ph1.w, phi8};

    // Pass 1: build chunk atoms in LOCAL coords, keep in registers.
    // Lane 0 starts from the world triple (its "local" == world).
    V3 A, Bv, C;
    if (k == 0){
        A = {NIX, NIY, NIZ}; Bv = {CAX, CAY, CAZ}; C = {CIX, CIY, CIZ};
    } else {
        A = {A0X, A0Y, 0.f}; Bv = {-1.54f, 0.f, 0.f}; C = {0.f, 0.f, 0.f};
    }
    V3 locA[8], locB[8], locC[8];     // statically indexed (full unroll)
    #pragma unroll
    for (int s = 0; s < 8; ++s){
        if (s0 + s < steps)
            step3(A, Bv, C, tpsi[s], tome[s], tphi[s]);
        locA[s] = A; locB[s] = Bv; locC[s] = C;   // k63 s7: dup, never staged
    }
    Xform V = frame_of(A, Bv, C);

    // Pass 2: in-wave inclusive scan, W_k = M_0 ∘ M_1 ∘ ... ∘ M_k.
    #pragma unroll
    for (int d = 1; d < 64; d <<= 1){
        Xform Pr = shfl_up_xf(V, d);
        if (k >= d) V = xcompose(Pr, V);
    }
    Xform Wp = shfl_up_xf(V, 1);      // W_{k-1} at lane k (lane 0 unused)

    // Pass 3: transform local atoms to world (one xapply per atom) + stage.
    if (k == 0){
        stage_row(lds, 0, {NIX, NIY, NIZ}, {CAX, CAY, CAZ}, {CIX, CIY, CIZ});
        #pragma unroll
        for (int s = 0; s < 8; ++s)
            stage_row(lds, s + 1, locA[s], locB[s], locC[s]);  // already world
    } else {
        #pragma unroll
        for (int s = 0; s < 8; ++s){
            if (s0 + s < steps)
                stage_row(lds, s0 + s + 1,
                          xapply(Wp, locA[s]), xapply(Wp, locB[s]), xapply(Wp, locC[s]));
        }
    }
    __syncthreads();

    // Pass 4: coalesced flush — unchanged from R6 (proven).
    float4* ol = (float4*)(out + (size_t)b * 4608u);
    const float4* ls = (const float4*)lds;
    #pragma unroll
    for (int i = 0; i < 18; ++i){
        int q = i * 64 + k;
        ol[q] = ls[q ^ ((q >> 6) & 7)];
    }
}

// ---- Fallback: sequential one-thread-per-chain (general sizes) ----
__global__ void nerf_seq_kernel(const float* __restrict__ phi,
                                const float* __restrict__ psi,
                                const float* __restrict__ omega,
                                float* __restrict__ out,
                                int B, int L, int steps){
    int b = blockIdx.x * blockDim.x + threadIdx.x;
    if (b >= B) return;
    V3 A  = {NIX, NIY, NIZ};
    V3 Bv = {CAX, CAY, CAZ};
    V3 C  = {CIX, CIY, CIZ};
    float* o = out + (size_t)b * 9u * (size_t)(steps + 1);
    o[0]=A.x;  o[1]=A.y;  o[2]=A.z;
    o[3]=Bv.x; o[4]=Bv.y; o[5]=Bv.z;
    o[6]=C.x;  o[7]=C.y;  o[8]=C.z;
    const float* pphi = phi   + (size_t)b * L;
    const float* ppsi = psi   + (size_t)b * L;
    const float* pome = omega + (size_t)b * L;
    for (int s = 0; s < steps; ++s){
        step3(A, Bv, C, ppsi[s], pome[s], pphi[s + 1]);
        float* os = o + 9u * (size_t)(s + 1);
        os[0]=A.x;  os[1]=A.y;  os[2]=A.z;
        os[3]=Bv.x; os[4]=Bv.y; os[5]=Bv.z;
        os[6]=C.x;  os[7]=C.y;  os[8]=C.z;
    }
}

extern "C" void kernel_launch(void* const* d_in, const int* in_sizes, int n_in,
                              void* d_out, int out_size, void* d_ws, size_t ws_size,
                              hipStream_t stream) {
    const float* phi   = (const float*)d_in[0];
    const float* psi   = (const float*)d_in[1];
    const float* omega = (const float*)d_in[2];
    float* out = (float*)d_out;

    const int L = 512;
    int B = in_sizes[0] / L;
    int steps = out_size / (9 * B) - 1;

    if (steps == 511 && in_sizes[0] == B * 512) {
        nerf_wave<<<B, 64, 0, stream>>>(phi, psi, omega, out, steps);
    } else {
        int block = 64;
        int grid = (B + block - 1) / block;
        nerf_seq_kernel<<<grid, block, 0, stream>>>(phi, psi, omega, out, B, L, steps);
    }
}

// Round 10
// 33.683 us; speedup vs baseline: 1.2677x; 1.0171x over previous
//
#include <hip/hip_runtime.h>

// NeRF backbone builder — combo of two HW-proven structures:
//   R8: 2 waves/chain, S=4, per-wave scan + LDS handoff of wave0's total.
//   R9: pass-3 = rigid TRANSFORM of register-resident pass-1 local atoms
//       (one xapply per atom) instead of a second step3 replay.
// Proven step3 renormalizing math ONLY (fast constant-scale math convicted
// R4/R5/R7). Swizzled LDS staging + coalesced float4 flush (proven R6/R8/R9).

struct V3 { float x, y, z; };

__device__ __forceinline__ V3 vsub(V3 a, V3 b){ return {a.x-b.x, a.y-b.y, a.z-b.z}; }
__device__ __forceinline__ V3 vcross(V3 a, V3 b){
    return {a.y*b.z - a.z*b.y, a.z*b.x - a.x*b.z, a.x*b.y - a.y*b.x};
}
__device__ __forceinline__ float vdot(V3 a, V3 b){ return a.x*b.x + a.y*b.y + a.z*b.z; }
__device__ __forceinline__ V3 vunit(V3 a){
    float r = rsqrtf(vdot(a,a));
    return {a.x*r, a.y*r, a.z*r};
}

struct Xform { V3 c0, c1, c2, t; };  // p' = c0*px + c1*py + c2*pz + t

__device__ __forceinline__ V3 xrot(const Xform& X, V3 p){
    return { X.c0.x*p.x + X.c1.x*p.y + X.c2.x*p.z,
             X.c0.y*p.x + X.c1.y*p.y + X.c2.y*p.z,
             X.c0.z*p.x + X.c1.z*p.y + X.c2.z*p.z };
}
__device__ __forceinline__ V3 xapply(const Xform& X, V3 p){
    V3 r = xrot(X, p);
    return { r.x + X.t.x, r.y + X.t.y, r.z + X.t.z };
}
__device__ __forceinline__ Xform xcompose(const Xform& A, const Xform& B){ // A∘B (B first)
    Xform R;
    R.c0 = xrot(A, B.c0);
    R.c1 = xrot(A, B.c1);
    R.c2 = xrot(A, B.c2);
    R.t  = xapply(A, B.t);
    return R;
}

__device__ __forceinline__ Xform frame_of(V3 A, V3 B, V3 C){
    V3 bc  = vunit(vsub(C, B));
    V3 n   = vunit(vcross(vsub(B, A), bc));
    V3 nbc = vcross(n, bc);
    return { bc, nbc, n, C };
}

__device__ __forceinline__ Xform shfl_up_xf(const Xform& X, int d){
    Xform R;
    R.c0.x = __shfl_up(X.c0.x, d); R.c0.y = __shfl_up(X.c0.y, d); R.c0.z = __shfl_up(X.c0.z, d);
    R.c1.x = __shfl_up(X.c1.x, d); R.c1.y = __shfl_up(X.c1.y, d); R.c1.z = __shfl_up(X.c1.z, d);
    R.c2.x = __shfl_up(X.c2.x, d); R.c2.y = __shfl_up(X.c2.y, d); R.c2.z = __shfl_up(X.c2.z, d);
    R.t.x  = __shfl_up(X.t.x,  d); R.t.y  = __shfl_up(X.t.y,  d); R.t.z  = __shfl_up(X.t.z,  d);
    return R;
}

// Bond constants: d0 = -L*cos(theta), Ls = L*sin(theta)
#define D0_CN   0.56630847f
#define LS_CN   1.21445243f
#define D0_NCA  0.75195559f
#define LS_NCA  1.25146426f
#define D0_CAC  0.50137496f
#define LS_CAC  1.45609861f

// Canonical incoming triple in its own frame (HW-validated R2/R3/R6/R8/R9)
#define A0X (-2.0153295f)
#define A0Y ( 1.3804571f)

// World init triple
#define NIX 17.047f
#define NIY 14.099f
#define NIZ  3.625f
#define CAX 16.967f
#define CAY 12.784f
#define CAZ  4.338f
#define CIX 15.685f
#define CIY 12.755f
#define CIZ  5.133f

__device__ __forceinline__ V3 place_dihedral(V3 a, V3 b, V3 c,
                                             float d0, float Ls, float tor){
    V3 ab = vsub(b, a);
    V3 bc = vunit(vsub(c, b));
    V3 n  = vunit(vcross(ab, bc));
    V3 nbc = vcross(n, bc);
    float sn, cs;
    __sincosf(tor, &sn, &cs);
    float d1 = Ls * cs;
    float d2 = Ls * sn;
    return { c.x + d0*bc.x + d1*nbc.x + d2*n.x,
             c.y + d0*bc.y + d1*nbc.y + d2*n.y,
             c.z + d0*bc.z + d1*nbc.z + d2*n.z };
}

__device__ __forceinline__ void step3(V3& A, V3& B, V3& C,
                                      float tpsi, float tome, float tphi){
    V3 dn  = place_dihedral(A, B, C,  D0_CN,  LS_CN,  tpsi);
    V3 dca = place_dihedral(B, C, dn, D0_NCA, LS_NCA, tome);
    V3 dc  = place_dihedral(C, dn, dca, D0_CAC, LS_CAC, tphi);
    A = dn; B = dca; C = dc;
}

// LDS float-index swizzle (involution, float4-consistent) — HW-validated R6/R8/R9.
__device__ __forceinline__ int swz(int F){ return F ^ (((F >> 8) & 7) << 2); }

__device__ __forceinline__ void stage_row(float* lds, int r, V3 a, V3 b, V3 c){
    int base = r * 9;
    lds[swz(base+0)] = a.x; lds[swz(base+1)] = a.y; lds[swz(base+2)] = a.z;
    lds[swz(base+3)] = b.x; lds[swz(base+4)] = b.y; lds[swz(base+5)] = b.z;
    lds[swz(base+6)] = c.x; lds[swz(base+7)] = c.y; lds[swz(base+8)] = c.z;
}

// ---- Fused kernel (steps==511, L==512): two waves per chain, S=4,
//      transform-based pass 3 ----
__global__ __launch_bounds__(128, 4)
void nerf_wave2t(const float* __restrict__ phi,
                 const float* __restrict__ psi,
                 const float* __restrict__ omega,
                 float* __restrict__ out,
                 int steps){
    const int L = 512;
    int b   = blockIdx.x;
    int tid = threadIdx.x;
    int w   = tid >> 6;                 // wave 0 / 1
    int k   = tid & 63;                 // lane in wave

    __shared__ float lds[4608];         // full chain, swizzled (18432 B)
    __shared__ float wc[12];            // wave0 total transform handoff

    const float* pphi = phi   + (size_t)b * L;
    const float* ppsi = psi   + (size_t)b * L;
    const float* pome = omega + (size_t)b * L;

    int s0 = tid << 2;                  // first step of this chunk

    float4 ps = *(const float4*)(ppsi + s0);
    float4 om = *(const float4*)(pome + s0);
    float4 ph = *(const float4*)(pphi + s0);
    float phn = __shfl_down(ph.x, 1);               // phi[s0+4] from lane k+1
    if (k == 63) phn = (w == 0) ? pphi[256] : 0.f;  // w1 k63 s3 is masked anyway
    float tpsi[4] = {ps.x, ps.y, ps.z, ps.w};
    float tome[4] = {om.x, om.y, om.z, om.w};
    float tphi[4] = {ph.y, ph.z, ph.w, phn};

    // ---- pass 1: chunk atoms in LOCAL coords, kept in registers ----
    V3 A, Bv, C;
    if (tid == 0){
        A = {NIX, NIY, NIZ}; Bv = {CAX, CAY, CAZ}; C = {CIX, CIY, CIZ};
    } else {
        A = {A0X, A0Y, 0.f}; Bv = {-1.54f, 0.f, 0.f}; C = {0.f, 0.f, 0.f};
    }
    V3 locA[4], locB[4], locC[4];       // statically indexed (full unroll)
    #pragma unroll
    for (int s = 0; s < 4; ++s){
        if (s0 + s < steps)
            step3(A, Bv, C, tpsi[s], tome[s], tphi[s]);
        locA[s] = A; locB[s] = Bv; locC[s] = C;   // masked slots never staged
    }
    Xform V = frame_of(A, Bv, C);

    // ---- per-wave inclusive scan: V_k = M_(w*64) ∘ ... ∘ M_(w*64+k) ----
    #pragma unroll
    for (int d = 1; d < 64; d <<= 1){
        Xform Pr = shfl_up_xf(V, d);
        if (k >= d) V = xcompose(Pr, V);
    }
    Xform Vp = shfl_up_xf(V, 1);        // wave-local prefix through lane k-1

    if (w == 0 && k == 63){             // publish wave0 total (through step 255)
        wc[0]=V.c0.x; wc[1]=V.c0.y; wc[2]=V.c0.z;
        wc[3]=V.c1.x; wc[4]=V.c1.y; wc[5]=V.c1.z;
        wc[6]=V.c2.x; wc[7]=V.c2.y; wc[8]=V.c2.z;
        wc[9]=V.t.x;  wc[10]=V.t.y; wc[11]=V.t.z;
    }
    __syncthreads();

    // ---- pass 3: transform local atoms to world + swizzled staging ----
    if (tid == 0){
        stage_row(lds, 0, {NIX, NIY, NIZ}, {CAX, CAY, CAZ}, {CIX, CIY, CIZ});
        #pragma unroll
        for (int s = 0; s < 4; ++s)
            stage_row(lds, s + 1, locA[s], locB[s], locC[s]);  // already world
    } else {
        Xform W;
        if (w == 0){
            W = Vp;
        } else {
            Xform Wc;
            Wc.c0 = {wc[0],wc[1],wc[2]};
            Wc.c1 = {wc[3],wc[4],wc[5]};
            Wc.c2 = {wc[6],wc[7],wc[8]};
            Wc.t  = {wc[9],wc[10],wc[11]};
            W = (k == 0) ? Wc : xcompose(Wc, Vp);
        }
        #pragma unroll
        for (int s = 0; s < 4; ++s){
            if (s0 + s < steps)
                stage_row(lds, s0 + s + 1,
                          xapply(W, locA[s]), xapply(W, locB[s]), xapply(W, locC[s]));
        }
    }
    __syncthreads();

    // ---- flush: 1152 float4, 128 threads x 9 iters, lane-consecutive ----
    float4* ol = (float4*)(out + (size_t)b * 4608u);
    const float4* ls = (const float4*)lds;
    #pragma unroll
    for (int i = 0; i < 9; ++i){
        int q = i * 128 + tid;
        ol[q] = ls[q ^ ((q >> 6) & 7)];
    }
}

// ---- Fallback: sequential one-thread-per-chain (general sizes) ----
__global__ void nerf_seq_kernel(const float* __restrict__ phi,
                                const float* __restrict__ psi,
                                const float* __restrict__ omega,
                                float* __restrict__ out,
                                int B, int L, int steps){
    int b = blockIdx.x * blockDim.x + threadIdx.x;
    if (b >= B) return;
    V3 A  = {NIX, NIY, NIZ};
    V3 Bv = {CAX, CAY, CAZ};
    V3 C  = {CIX, CIY, CIZ};
    float* o = out + (size_t)b * 9u * (size_t)(steps + 1);
    o[0]=A.x;  o[1]=A.y;  o[2]=A.z;
    o[3]=Bv.x; o[4]=Bv.y; o[5]=Bv.z;
    o[6]=C.x;  o[7]=C.y;  o[8]=C.z;
    const float* pphi = phi   + (size_t)b * L;
    const float* ppsi = psi   + (size_t)b * L;
    const float* pome = omega + (size_t)b * L;
    for (int s = 0; s < steps; ++s){
        step3(A, Bv, C, ppsi[s], pome[s], pphi[s + 1]);
        float* os = o + 9u * (size_t)(s + 1);
        os[0]=A.x;  os[1]=A.y;  os[2]=A.z;
        os[3]=Bv.x; os[4]=Bv.y; os[5]=Bv.z;
        os[6]=C.x;  os[7]=C.y;  os[8]=C.z;
    }
}

extern "C" void kernel_launch(void* const* d_in, const int* in_sizes, int n_in,
                              void* d_out, int out_size, void* d_ws, size_t ws_size,
                              hipStream_t stream) {
    const float* phi   = (const float*)d_in[0];
    const float* psi   = (const float*)d_in[1];
    const float* omega = (const float*)d_in[2];
    float* out = (float*)d_out;

    const int L = 512;
    int B = in_sizes[0] / L;
    int steps = out_size / (9 * B) - 1;

    if (steps == 511 && in_sizes[0] == B * 512) {
        nerf_wave2t<<<B, 128, 0, stream>>>(phi, psi, omega, out, steps);
    } else {
        int block = 64;
        int grid = (B + block - 1) / block;
        nerf_seq_kernel<<<grid, block, 0, stream>>>(phi, psi, omega, out, B, L, steps);
    }
}